// Round 9
// baseline (628.960 us; speedup 1.0000x reference)
//
#include <hip/hip_runtime.h>

#define N_ITEMS 200000
#define EPSV2 1e-16f   // eps on SQUARED norm: max(sqrt(x),1e-8)=sqrt(max(x,1e-16))
#define INV_TEMP 10.0f
#define NSLOT 16

// ---- workspace layout (bytes) for the two-phase path ----
#define U2_OFF   0UL            // 200000*128 bf16 = 51.2 MB (g2 normalized)
#define V2_OFF   51200000UL     // s2 normalized
#define W_OFF    102400000UL    // sa normalized
#define PCG_OFF  153600000UL    // 200000 f32 positive cos (graph)
#define PCS_OFF  154400000UL
#define PCC_OFF  155200000UL
#define LOSS_OFF 156000000UL    // NSLOT*4 f32
#define WS_NEEDED (LOSS_OFF + NSLOT * 16UL)

typedef float f32x4 __attribute__((ext_vector_type(4)));
typedef unsigned short u16x8 __attribute__((ext_vector_type(8)));

__device__ __forceinline__ float softplus_f(float x) {
    return fmaxf(x, 0.0f) + log1pf(expf(-fabsf(x)));
}
__device__ __forceinline__ float dot8(f32x4 a0, f32x4 a1, f32x4 b0, f32x4 b1) {
    f32x4 t = a0 * b0 + a1 * b1;
    return t.x + t.y + t.z + t.w;
}
// bf16 round-to-nearest-even encode / decode
__device__ __forceinline__ unsigned short f2bf(float x) {
    unsigned u = __float_as_uint(x);
    u += 0x7FFFu + ((u >> 16) & 1u);
    return (unsigned short)(u >> 16);
}
__device__ __forceinline__ u16x8 pack_bf8(f32x4 a, f32x4 b) {
    u16x8 r;
    r[0]=f2bf(a.x); r[1]=f2bf(a.y); r[2]=f2bf(a.z); r[3]=f2bf(a.w);
    r[4]=f2bf(b.x); r[5]=f2bf(b.y); r[6]=f2bf(b.z); r[7]=f2bf(b.w);
    return r;
}
__device__ __forceinline__ void unpack_bf8(u16x8 h, f32x4& a, f32x4& b) {
    a.x=__uint_as_float(((unsigned)h[0])<<16); a.y=__uint_as_float(((unsigned)h[1])<<16);
    a.z=__uint_as_float(((unsigned)h[2])<<16); a.w=__uint_as_float(((unsigned)h[3])<<16);
    b.x=__uint_as_float(((unsigned)h[4])<<16); b.y=__uint_as_float(((unsigned)h[5])<<16);
    b.z=__uint_as_float(((unsigned)h[6])<<16); b.w=__uint_as_float(((unsigned)h[7])<<16);
}

__global__ void mvr_init_ws(float* loss, int n) {
    if ((int)threadIdx.x < n) loss[threadIdx.x] = 0.0f;
}

// ---------------- Phase 1: pure streaming, ZERO gathers ----------------
// Flat launch is safe here: no random reads -> FETCH is structurally
// compulsory at any occupancy (the R1/R2/R5 inflation was gather re-fetch).
// Computes: out embeddings (exact fp32), positive cosines, and bf16
// normalized aux rows u2,v2,w in the lane-permuted layout (lane l holds
// floats {4l..4l+3, 64+4l..67+4l}); phase 2 reads the same permutation, and
// dot products are order-invariant, so the permutation is harmless.
__global__ __launch_bounds__(256) void mvr_phase1(
    const float* __restrict__ g1, const float* __restrict__ g2,
    const float* __restrict__ s1, const float* __restrict__ s2,
    const float* __restrict__ att_w,
    float* __restrict__ out, unsigned char* __restrict__ ws)
{
    const int tid = threadIdx.x;
    const int lane = tid & 63;
    const int g = lane >> 4;
    const int l = lane & 15;
    const int waveId = (blockIdx.x << 2) + (tid >> 6);
    const int item = (waveId << 2) + g;
    const size_t rb = (size_t)item * 32;

    const f32x4* G1 = (const f32x4*)g1;
    const f32x4* G2 = (const f32x4*)g2;
    const f32x4* S1 = (const f32x4*)s1;
    const f32x4* S2 = (const f32x4*)s2;
    f32x4* Op = (f32x4*)out;
    const f32x4* Wt = (const f32x4*)att_w;
    const f32x4 wa0 = Wt[l], wa1 = Wt[16 + l];
    const f32x4 wb0 = Wt[32 + l], wb1 = Wt[48 + l];

    f32x4 G1a = G1[rb + l], G1b = G1[rb + 16 + l];
    f32x4 G2a = G2[rb + l], G2b = G2[rb + 16 + l];
    f32x4 S1a = S1[rb + l], S1b = S1[rb + 16 + l];
    f32x4 S2a = S2[rb + l], S2b = S2[rb + 16 + l];

    f32x4 GAa = (G1a + G2a) * 0.5f, GAb = (G1b + G2b) * 0.5f;
    f32x4 SAa = (S1a + S2a) * 0.5f, SAb = (S1b + S2b) * 0.5f;

    float v[10];
    v[0] = dot8(G1a, G1b, G2a, G2b);   // g1.g2
    v[1] = dot8(G1a, G1b, G1a, G1b);   // |g1|^2
    v[2] = dot8(G2a, G2b, G2a, G2b);   // |g2|^2
    v[3] = dot8(S1a, S1b, S2a, S2b);
    v[4] = dot8(S1a, S1b, S1a, S1b);
    v[5] = dot8(S2a, S2b, S2a, S2b);
    v[6] = dot8(GAa, GAb, SAa, SAb);   // ga.sa
    v[7] = dot8(GAa, GAb, GAa, GAb);   // |ga|^2
    v[8] = dot8(SAa, SAb, SAa, SAb);   // |sa|^2
    v[9] = dot8(GAa, GAb, wa0, wa1) + dot8(SAa, SAb, wb0, wb1); // att dot

    #pragma unroll
    for (int off = 8; off > 0; off >>= 1) {
        #pragma unroll
        for (int k = 0; k < 10; k++)
            v[k] += __shfl_xor(v[k], off, 64);
    }

    const float ig1 = rsqrtf(fmaxf(v[1], EPSV2));
    const float ig2 = rsqrtf(fmaxf(v[2], EPSV2));
    const float is1 = rsqrtf(fmaxf(v[4], EPSV2));
    const float is2 = rsqrtf(fmaxf(v[5], EPSV2));
    const float iga = rsqrtf(fmaxf(v[7], EPSV2));
    const float isa = rsqrtf(fmaxf(v[8], EPSV2));

    // bf16 normalized aux rows (row = 16 u16x8 units, lane-permuted)
    u16x8* U2 = (u16x8*)(ws + U2_OFF);
    u16x8* V2 = (u16x8*)(ws + V2_OFF);
    u16x8* Wn = (u16x8*)(ws + W_OFF);
    const size_t ra = (size_t)item * 16 + l;
    U2[ra] = pack_bf8(G2a * ig2, G2b * ig2);
    V2[ra] = pack_bf8(S2a * is2, S2b * is2);
    Wn[ra] = pack_bf8(SAa * isa, SAb * isa);

    if (l == 0) {
        ((float*)(ws + PCG_OFF))[item] = v[0] * ig1 * ig2;
        ((float*)(ws + PCS_OFF))[item] = v[3] * is1 * is2;
        ((float*)(ws + PCC_OFF))[item] = v[6] * iga * isa;
    }

    const float alpha = 1.0f / (1.0f + expf(-v[9]));
    Op[rb + l]      = SAa + alpha * (GAa - SAa);
    Op[rb + 16 + l] = SAb + alpha * (GAb - SAb);
}

// ---------------- Phase 2: the gathers, now 256 B bf16 rows ----------------
// Gather target set = u2,v2,w = 153.6 MB < 256 MB L3 -> re-fetch is
// structurally bounded; flat high-occupancy launch is safe. w_i is
// pre-normalized (|w|=1) so ccn = dot(w_i, w_jc) directly.
__global__ __launch_bounds__(256) void mvr_phase2(
    const float* __restrict__ g1, const float* __restrict__ s1,
    const int* __restrict__ neg_g, const int* __restrict__ neg_s,
    const int* __restrict__ neg_c, unsigned char* __restrict__ ws)
{
    const int tid = threadIdx.x;
    const int lane = tid & 63;
    const int g = lane >> 4;
    const int l = lane & 15;
    const int waveId = (blockIdx.x << 2) + (tid >> 6);
    const int item = (waveId << 2) + g;

    const int jg = neg_g[item];
    const int js = neg_s[item];
    const int jc = neg_c[item];

    const f32x4* G1 = (const f32x4*)g1;
    const f32x4* S1 = (const f32x4*)s1;
    const u16x8* U2 = (const u16x8*)(ws + U2_OFF);
    const u16x8* V2 = (const u16x8*)(ws + V2_OFF);
    const u16x8* Wn = (const u16x8*)(ws + W_OFF);

    const size_t rb = (size_t)item * 32;
    f32x4 G1a = G1[rb + l], G1b = G1[rb + 16 + l];
    f32x4 S1a = S1[rb + l], S1b = S1[rb + 16 + l];
    u16x8 hWi = Wn[(size_t)item * 16 + l];
    u16x8 hU2 = U2[(size_t)jg * 16 + l];
    u16x8 hV2 = V2[(size_t)js * 16 + l];
    u16x8 hWj = Wn[(size_t)jc * 16 + l];

    f32x4 u2a, u2b, v2a, v2b, wia, wib, wja, wjb;
    unpack_bf8(hU2, u2a, u2b);
    unpack_bf8(hV2, v2a, v2b);
    unpack_bf8(hWi, wia, wib);
    unpack_bf8(hWj, wja, wjb);

    float v[5];
    v[0] = dot8(G1a, G1b, u2a, u2b);   // g1 . u2[jg]
    v[1] = dot8(G1a, G1b, G1a, G1b);   // |g1|^2
    v[2] = dot8(S1a, S1b, v2a, v2b);
    v[3] = dot8(S1a, S1b, S1a, S1b);
    v[4] = dot8(wia, wib, wja, wjb);   // w_i . w_jc (both unit)

    #pragma unroll
    for (int off = 8; off > 0; off >>= 1) {
        #pragma unroll
        for (int k = 0; k < 5; k++)
            v[k] += __shfl_xor(v[k], off, 64);
    }

    const float cgn = v[0] * rsqrtf(fmaxf(v[1], EPSV2));
    const float csn = v[2] * rsqrtf(fmaxf(v[3], EPSV2));
    const float ccn = v[4];

    const float pcg = ((const float*)(ws + PCG_OFF))[item];
    const float pcs = ((const float*)(ws + PCS_OFF))[item];
    const float pcc = ((const float*)(ws + PCC_OFF))[item];

    float accG = softplus_f((cgn - pcg) * INV_TEMP);
    float accS = softplus_f((csn - pcs) * INV_TEMP);
    float accC = softplus_f((ccn - pcc) * INV_TEMP);

    accG += __shfl_xor(accG, 16, 64); accG += __shfl_xor(accG, 32, 64);
    accS += __shfl_xor(accS, 16, 64); accS += __shfl_xor(accS, 32, 64);
    accC += __shfl_xor(accC, 16, 64); accC += __shfl_xor(accC, 32, 64);

    __shared__ float sh[4][3];
    const int wave = tid >> 6;
    if (lane == 0) { sh[wave][0] = accG; sh[wave][1] = accS; sh[wave][2] = accC; }
    __syncthreads();
    if (tid == 0) {
        float a = 0.f, b = 0.f, c = 0.f;
        #pragma unroll
        for (int w = 0; w < 4; w++) { a += sh[w][0]; b += sh[w][1]; c += sh[w][2]; }
        float* loss = (float*)(ws + LOSS_OFF);
        const int slot = (blockIdx.x & (NSLOT - 1)) * 4;
        atomicAdd(&loss[slot + 0], a);
        atomicAdd(&loss[slot + 1], b);
        atomicAdd(&loss[slot + 2], c);
    }
}

// ---------------- Fallback: R6 single-phase (best known: 221 us) ----------------
__global__ __launch_bounds__(256, 3) void mvr_single(
    const float* __restrict__ g1, const float* __restrict__ g2,
    const float* __restrict__ s1, const float* __restrict__ s2,
    const float* __restrict__ att_w,
    const int* __restrict__ neg_g, const int* __restrict__ neg_s,
    const int* __restrict__ neg_c,
    float* __restrict__ out, float* __restrict__ loss_acc)
{
    const int tid = threadIdx.x;
    const int lane = tid & 63;
    const int g = lane >> 4;
    const int l = lane & 15;
    const int wavesPerBlock = blockDim.x >> 6;
    const int waveId = blockIdx.x * wavesPerBlock + (tid >> 6);
    const int waveStride = gridDim.x * wavesPerBlock;
    const int stride4 = waveStride * 4;

    const f32x4* Wt = (const f32x4*)att_w;
    const f32x4 wa0 = Wt[l], wa1 = Wt[16 + l];
    const f32x4 wb0 = Wt[32 + l], wb1 = Wt[48 + l];

    const f32x4* G1p = (const f32x4*)g1;
    const f32x4* G2p = (const f32x4*)g2;
    const f32x4* S1p = (const f32x4*)s1;
    const f32x4* S2p = (const f32x4*)s2;
    f32x4* Op = (f32x4*)out;

    float accG = 0.0f, accS = 0.0f, accC = 0.0f;
    int jg, js, jc;
    {
        const int item0 = waveId * 4 + g;
        jg = neg_g[item0]; js = neg_s[item0]; jc = neg_c[item0];
    }

    for (int base = waveId * 4; base < N_ITEMS; base += stride4) {
        const int item = base + g;
        const size_t rb = (size_t)item * 32;
        const size_t rg = (size_t)jg * 32, rs = (size_t)js * 32, rc = (size_t)jc * 32;

        f32x4 G1a = G1p[rb + l], G1b = G1p[rb + 16 + l];
        f32x4 G2a = G2p[rb + l], G2b = G2p[rb + 16 + l];
        f32x4 S1a = S1p[rb + l], S1b = S1p[rb + 16 + l];
        f32x4 S2a = S2p[rb + l], S2b = S2p[rb + 16 + l];
        f32x4 Gna = G2p[rg + l], Gnb = G2p[rg + 16 + l];
        f32x4 Sna = S2p[rs + l], Snb = S2p[rs + 16 + l];
        f32x4 C1a = S1p[rc + l], C1b = S1p[rc + 16 + l];
        f32x4 C2a = S2p[rc + l], C2b = S2p[rc + 16 + l];

        {
            const int nbase = base + stride4;
            const int nitem = (nbase < N_ITEMS) ? (nbase + g) : item;
            jg = neg_g[nitem]; js = neg_s[nitem]; jc = neg_c[nitem];
        }

        __builtin_amdgcn_sched_barrier(0);

        f32x4 GAa = (G1a + G2a) * 0.5f, GAb = (G1b + G2b) * 0.5f;
        f32x4 SAa = (S1a + S2a) * 0.5f, SAb = (S1b + S2b) * 0.5f;

        float v[16];
        v[0]  = dot8(G1a, G1b, G2a, G2b);
        v[1]  = dot8(G1a, G1b, G1a, G1b);
        v[2]  = dot8(G2a, G2b, G2a, G2b);
        v[5]  = dot8(S1a, S1b, S2a, S2b);
        v[6]  = dot8(S1a, S1b, S1a, S1b);
        v[7]  = dot8(S2a, S2b, S2a, S2b);
        v[10] = dot8(GAa, GAb, SAa, SAb);
        v[11] = dot8(GAa, GAb, GAa, GAb);
        v[12] = dot8(SAa, SAb, SAa, SAb);
        v[15] = dot8(GAa, GAb, wa0, wa1) + dot8(SAa, SAb, wb0, wb1);

        __builtin_amdgcn_sched_barrier(0);

        f32x4 CNa = (C1a + C2a) * 0.5f, CNb = (C1b + C2b) * 0.5f;
        v[3]  = dot8(G1a, G1b, Gna, Gnb);
        v[4]  = dot8(Gna, Gnb, Gna, Gnb);
        v[8]  = dot8(S1a, S1b, Sna, Snb);
        v[9]  = dot8(Sna, Snb, Sna, Snb);
        v[13] = dot8(GAa, GAb, CNa, CNb);
        v[14] = dot8(CNa, CNb, CNa, CNb);

        #pragma unroll
        for (int off = 8; off > 0; off >>= 1) {
            #pragma unroll
            for (int k = 0; k < 16; k++)
                v[k] += __shfl_xor(v[k], off, 64);
        }

        const float cgp = v[0] * rsqrtf(fmaxf(v[1] * v[2], EPSV2));
        const float cgn = v[3] * rsqrtf(fmaxf(v[1] * v[4], EPSV2));
        accG += softplus_f((cgn - cgp) * INV_TEMP);
        const float csp = v[5] * rsqrtf(fmaxf(v[6] * v[7], EPSV2));
        const float csn = v[8] * rsqrtf(fmaxf(v[6] * v[9], EPSV2));
        accS += softplus_f((csn - csp) * INV_TEMP);
        const float ccp = v[10] * rsqrtf(fmaxf(v[11] * v[12], EPSV2));
        const float ccn = v[13] * rsqrtf(fmaxf(v[11] * v[14], EPSV2));
        accC += softplus_f((ccn - ccp) * INV_TEMP);

        const float alpha = 1.0f / (1.0f + expf(-v[15]));
        Op[rb + l]      = SAa + alpha * (GAa - SAa);
        Op[rb + 16 + l] = SAb + alpha * (GAb - SAb);
    }

    accG += __shfl_xor(accG, 16, 64); accG += __shfl_xor(accG, 32, 64);
    accS += __shfl_xor(accS, 16, 64); accS += __shfl_xor(accS, 32, 64);
    accC += __shfl_xor(accC, 16, 64); accC += __shfl_xor(accC, 32, 64);

    __shared__ float sh[4][3];
    const int wave = tid >> 6;
    if (lane == 0) { sh[wave][0] = accG; sh[wave][1] = accS; sh[wave][2] = accC; }
    __syncthreads();
    if (tid == 0) {
        float a = 0.f, b = 0.f, c = 0.f;
        #pragma unroll
        for (int w = 0; w < 4; w++) { a += sh[w][0]; b += sh[w][1]; c += sh[w][2]; }
        atomicAdd(&loss_acc[0], a);
        atomicAdd(&loss_acc[1], b);
        atomicAdd(&loss_acc[2], c);
    }
}

__global__ void mvr_finalize(const float* __restrict__ loss_acc, int nslots,
                             float* __restrict__ out_scalar) {
    if (threadIdx.x == 0) {
        float t = 0.0f;
        for (int s = 0; s < nslots; s++)
            t += loss_acc[s * 4 + 0] + loss_acc[s * 4 + 1] + loss_acc[s * 4 + 2];
        out_scalar[0] = t * (1.0f / (float)N_ITEMS);
    }
}

extern "C" void kernel_launch(void* const* d_in, const int* in_sizes, int n_in,
                              void* d_out, int out_size, void* d_ws, size_t ws_size,
                              hipStream_t stream) {
    const float* g1    = (const float*)d_in[0];
    const float* g2    = (const float*)d_in[1];
    const float* s1    = (const float*)d_in[2];
    const float* s2    = (const float*)d_in[3];
    const float* att_w = (const float*)d_in[4];
    const int*   neg_g = (const int*)d_in[5];
    const int*   neg_s = (const int*)d_in[6];
    const int*   neg_c = (const int*)d_in[7];
    float* out = (float*)d_out;
    unsigned char* ws = (unsigned char*)d_ws;

    if (ws_size >= WS_NEEDED) {
        float* loss = (float*)(ws + LOSS_OFF);
        mvr_init_ws<<<1, 64, 0, stream>>>(loss, NSLOT * 4);
        mvr_phase1<<<12500, 256, 0, stream>>>(g1, g2, s1, s2, att_w, out, ws);
        mvr_phase2<<<12500, 256, 0, stream>>>(g1, s1, neg_g, neg_s, neg_c, ws);
        mvr_finalize<<<1, 64, 0, stream>>>(loss, NSLOT, out + (size_t)N_ITEMS * 128);
    } else {
        float* loss = (float*)ws;
        mvr_init_ws<<<1, 64, 0, stream>>>(loss, 4);
        mvr_single<<<3125, 256, 0, stream>>>(g1, g2, s1, s2, att_w,
                                             neg_g, neg_s, neg_c, out, loss);
        mvr_finalize<<<1, 64, 0, stream>>>(loss, 1, out + (size_t)N_ITEMS * 128);
    }
}